// Round 5
// baseline (489.274 us; speedup 1.0000x reference)
//
#include <hip/hip_runtime.h>

typedef unsigned short u16;
typedef __attribute__((ext_vector_type(8))) short bf16x8;
typedef __attribute__((ext_vector_type(4))) float f32x4;
typedef __attribute__((ext_vector_type(4))) unsigned int u32x4;

#define GAS __attribute__((address_space(1)))
#define LAS __attribute__((address_space(3)))

__device__ __forceinline__ void gload16(const void* g, void* l) {
  __builtin_amdgcn_global_load_lds((GAS void*)g, (LAS void*)l, 16, 0, 0);
}
__device__ __forceinline__ u16 f2b(float x) {
  union { float f; unsigned u; } c; c.f = x;
  unsigned r = c.u + 0x7fffu + ((c.u >> 16) & 1u);
  return (u16)(r >> 16);
}
__device__ __forceinline__ float b2f(u16 h) {
  union { unsigned u; float f; } c; c.u = ((unsigned)h) << 16;
  return c.f;
}

// ---------------- fp32 -> bf16 conversion (8 elems/thread) ----------------
__global__ __launch_bounds__(256) void cvt_bf16(const float* __restrict__ src,
                                                u16* __restrict__ dst, int n8) {
  int i = blockIdx.x * 256 + threadIdx.x;
  if (i >= n8) return;
  const float4* s4 = (const float4*)src;
  float4 a = s4[(size_t)i * 2], b = s4[(size_t)i * 2 + 1];
  u32x4 v;
  v[0] = (unsigned)f2b(a.x) | ((unsigned)f2b(a.y) << 16);
  v[1] = (unsigned)f2b(a.z) | ((unsigned)f2b(a.w) << 16);
  v[2] = (unsigned)f2b(b.x) | ((unsigned)f2b(b.y) << 16);
  v[3] = (unsigned)f2b(b.z) | ((unsigned)f2b(b.w) << 16);
  *(u32x4*)(dst + (size_t)i * 8) = v;
}

// ---------------- GEMM: C[m,n] = sum_k A[m,k]*B[n,k]  (B given row=n, K-major)
// 128x128 tile, BK=32, 4 waves (2x2), each wave 64x64 via 4x4 mfma frags.
// LDS 16B-slot involution swizzle: phys(row,kc) = row*4 + (kc ^ (row&3)).
// MODE 0 scatter: Q[B,32,S,128], K[B,8,S,128], V TRANSPOSED [B,8,128,S] (bf16)
// MODE 1: plain fp32 epilogue into Dout[m*2048+n]
template <int MODE>
__global__ __launch_bounds__(256) void gemm_bt(
    const u16* __restrict__ A, const u16* __restrict__ B,
    u16* __restrict__ Dq, u16* __restrict__ Dk, u16* __restrict__ Dv,
    float* __restrict__ Dout, int M, int N, int K) {
  __shared__ __attribute__((aligned(16))) u16 As[128 * 32];
  __shared__ __attribute__((aligned(16))) u16 Bs[128 * 32];
  const int tid = threadIdx.x;
  const int lane = tid & 63;
  const int w = tid >> 6;
  const int wr = w >> 1, wc = w & 1;
  const int r = lane & 15, g = lane >> 4;
  const int m0 = blockIdx.y * 128, n0 = blockIdx.x * 128;
  (void)M; (void)N;

  f32x4 acc[4][4];
#pragma unroll
  for (int i = 0; i < 4; ++i)
#pragma unroll
    for (int j = 0; j < 4; ++j) acc[i][j] = (f32x4){0.f, 0.f, 0.f, 0.f};

  for (int k0 = 0; k0 < K; k0 += 32) {
#pragma unroll
    for (int c = 0; c < 2; ++c) {
      int t = c * 256 + tid;          // 16B slot index in [0,512)
      int row = t >> 2;               // row unchanged by swizzle (XOR hits bits 0-1)
      int kc = (t & 3) ^ ((t >> 2) & 3);
      gload16(A + (size_t)(m0 + row) * K + k0 + kc * 8, (char*)As + c * 4096 + w * 1024);
      gload16(B + (size_t)(n0 + row) * K + k0 + kc * 8, (char*)Bs + c * 4096 + w * 1024);
    }
    __syncthreads();  // drains vmcnt; LDS tiles ready

    bf16x8 af[4], bfr[4];
#pragma unroll
    for (int mi = 0; mi < 4; ++mi) {
      int ro = wr * 64 + mi * 16 + r;
      int slot = (ro * 4 + g) ^ (ro & 3);
      af[mi] = *(const bf16x8*)((const char*)As + slot * 16);
    }
#pragma unroll
    for (int ni = 0; ni < 4; ++ni) {
      int ro = wc * 64 + ni * 16 + r;
      int slot = (ro * 4 + g) ^ (ro & 3);
      bfr[ni] = *(const bf16x8*)((const char*)Bs + slot * 16);
    }
#pragma unroll
    for (int mi = 0; mi < 4; ++mi)
#pragma unroll
      for (int ni = 0; ni < 4; ++ni)
        acc[mi][ni] = __builtin_amdgcn_mfma_f32_16x16x32_bf16(af[mi], bfr[ni],
                                                              acc[mi][ni], 0, 0, 0);
    __syncthreads();  // all reads done before restage
  }

  // Epilogue. D layout: col = lane&15 (=r), row = (lane>>4)*4 + j (=g*4+j).
#pragma unroll
  for (int mi = 0; mi < 4; ++mi)
#pragma unroll
    for (int ni = 0; ni < 4; ++ni)
#pragma unroll
      for (int j = 0; j < 4; ++j) {
        int m = m0 + wr * 64 + mi * 16 + g * 4 + j;
        int n = n0 + wc * 64 + ni * 16 + r;
        float v = acc[mi][ni][j];
        if (MODE == 0) {
          u16 hv = f2b(v);
          int b = m >> 11, s = m & 2047;
          if (n < 4096) {
            Dq[(((size_t)b * 32 + (n >> 7)) * 2048 + s) * 128 + (n & 127)] = hv;
          } else if (n < 5120) {
            int nn = n - 4096;
            Dk[(((size_t)b * 8 + (nn >> 7)) * 2048 + s) * 128 + (nn & 127)] = hv;
          } else {
            int nn = n - 5120;  // V: write transposed [b, hkv, d, s]
            Dv[(((size_t)b * 8 + (nn >> 7)) * 128 + (nn & 127)) * 2048 + s] = hv;
          }
        } else {
          Dout[(size_t)m * 2048 + n] = v;
        }
      }
}

// ---------------- fused per-head RMSNorm + RoPE (in place, bf16) ----------------
__global__ __launch_bounds__(256) void rms_rope(u16* __restrict__ X,
                                                const float* __restrict__ cosT,
                                                const float* __restrict__ sinT,
                                                const float* __restrict__ nw,
                                                int nrows, float oscale) {
  int idx = blockIdx.x * 256 + threadIdx.x;
  int row = idx >> 6;
  int lane = idx & 63;
  if (row >= nrows) return;
  int s = row & 2047;  // S = 2048
  u16* rp = X + (size_t)row * 128;
  float x0 = b2f(rp[lane]);
  float x1 = b2f(rp[lane + 64]);
  float ss = x0 * x0 + x1 * x1;
#pragma unroll
  for (int m = 32; m >= 1; m >>= 1) ss += __shfl_xor(ss, m);
  float inv = rsqrtf(ss * (1.0f / 128.0f) + 1e-6f);
  x0 *= inv * nw[lane];
  x1 *= inv * nw[lane + 64];
  float c0 = cosT[s * 128 + lane], s0 = sinT[s * 128 + lane];
  float c1 = cosT[s * 128 + lane + 64], s1 = sinT[s * 128 + lane + 64];
  rp[lane] = f2b((x0 * c0 - x1 * s0) * oscale);
  rp[lane + 64] = f2b((x1 * c1 + x0 * s1) * oscale);
}

// ---------------- causal GQA flash attention (paired Q-tiles) ----------------
// block p handles Q-tiles {31-p, p} (uniform 33 KV-units). 4 waves x 16 q-rows.
// KVBLK = 64. SWAPPED QK^T (lane owns q-row w*16+r; in-lane softmax, exp2).
// K staged [64][128] via global_load_lds, granule swizzle phys = kc ^ (krow&7).
// V^T (global [b,hkv,128,2048]) staged [128 d][64 kv] via global_load_lds,
//   source pre-swizzled with involution phys_gran = kvg ^ ((d>>1)&7), dest linear.
__global__ __launch_bounds__(256) void attn_fwd(const u16* __restrict__ Q,
                                                const u16* __restrict__ Kg,
                                                const u16* __restrict__ Vg,
                                                u16* __restrict__ AO) {
  __shared__ __attribute__((aligned(16))) u16 Ks[64 * 128];
  __shared__ __attribute__((aligned(16))) u16 Vt[128 * 64];
  __shared__ __attribute__((aligned(16))) u16 Plds[4][16 * 64];
  const int tid = threadIdx.x;
  const int lane = tid & 63;
  const int w = tid >> 6;
  const int r = lane & 15, g = lane >> 4;
  const int p = blockIdx.x, h = blockIdx.y, b = blockIdx.z;
  const int hkv = h >> 2;

  const u16* Kp = Kg + (((size_t)b * 8 + hkv) * 2048) * 128;
  const u16* Vp = Vg + (((size_t)b * 8 + hkv) * 128) * 2048;  // transposed head base

#pragma unroll 1
  for (int phase = 0; phase < 2; ++phase) {
    const int qt = phase == 0 ? (31 - p) : p;
    const u16* Qp = Q + (((size_t)b * 32 + h) * 2048 + qt * 64 + w * 16) * 128;

    // Q fragments (B-operand): row q = r, k(d) = kk*32 + g*8 + e
    bf16x8 qf[4];
#pragma unroll
    for (int kk = 0; kk < 4; ++kk)
      qf[kk] = *(const bf16x8*)(Qp + r * 128 + kk * 32 + g * 8);

    f32x4 off[8];
#pragma unroll
    for (int i = 0; i < 8; ++i) off[i] = (f32x4){0.f, 0.f, 0.f, 0.f};
    float mrun = -1e30f, lrun = 0.f;  // per-lane: q-row = w*16 + r

    const int qg = qt * 64 + w * 16 + r;  // this lane's global q row
    const int nu = qt + 1;                // 64-wide KV units

    for (int kt = 0; kt < nu; ++kt) {
      // ---- stage K via global_load_lds (swizzled granules)
#pragma unroll
      for (int c = 0; c < 4; ++c) {
        int t = c * 256 + tid;  // 16B slot in [0,1024)
        int krow = t >> 4;
        int kcc = (t & 15) ^ (krow & 7);
        gload16(Kp + (size_t)(kt * 64 + krow) * 128 + kcc * 8,
                (char*)Ks + c * 4096 + w * 1024);
      }
      // ---- stage V^T via global_load_lds (pre-swizzled source, linear dest)
#pragma unroll
      for (int c = 0; c < 4; ++c) {
        int t = c * 256 + tid;  // 16B slot in [0,1024): d = t>>3, phys gran = t&7
        int d = t >> 3;
        int kvg = (t & 7) ^ ((d >> 1) & 7);
        gload16(Vp + (size_t)d * 2048 + kt * 64 + kvg * 8,
                (char*)Vt + c * 4096 + w * 1024);
      }
      __syncthreads();

      // ---- S^T = K Q^T (swapped): D col = q = r, D row = kv = ni*16 + g*4 + j
      f32x4 sc[4];
#pragma unroll
      for (int ni = 0; ni < 4; ++ni) {
        f32x4 a = (f32x4){0.f, 0.f, 0.f, 0.f};
        int ro = ni * 16 + r;
#pragma unroll
        for (int kk = 0; kk < 4; ++kk) {
          int slot = (ro * 16 + kk * 4 + g) ^ (ro & 7);
          bf16x8 kf = *(const bf16x8*)((const char*)Ks + slot * 16);
          a = __builtin_amdgcn_mfma_f32_16x16x32_bf16(kf, qf[kk], a, 0, 0, 0);
        }
        sc[ni] = a;
      }

      // ---- mask (diagonal unit only) + in-lane max
      float pm = -3e30f;
      if (kt == qt) {
#pragma unroll
        for (int ni = 0; ni < 4; ++ni)
#pragma unroll
          for (int j = 0; j < 4; ++j) {
            int kvg = kt * 64 + ni * 16 + g * 4 + j;
            float sv = sc[ni][j];
            sv = (kvg > qg) ? -1e30f : sv;
            sc[ni][j] = sv;
            pm = fmaxf(pm, sv);
          }
      } else {
#pragma unroll
        for (int ni = 0; ni < 4; ++ni)
#pragma unroll
          for (int j = 0; j < 4; ++j) pm = fmaxf(pm, sc[ni][j]);
      }
      pm = fmaxf(pm, __shfl_xor(pm, 16));
      pm = fmaxf(pm, __shfl_xor(pm, 32));

      // ---- defer-rescale (log2 units, THR=11 ~ e^7.6)
      if (__any(pm > mrun + 11.0f)) {
        float mn = fmaxf(mrun, pm);
        float sclq = exp2f(mrun - mn);
        mrun = mn;
        lrun *= sclq;
        // redistribute scl to PV-output rows (q16 = g*4+j lives at lane r = g*4+j)
        float s0 = __shfl(sclq, g * 4 + 0);
        float s1 = __shfl(sclq, g * 4 + 1);
        float s2 = __shfl(sclq, g * 4 + 2);
        float s3 = __shfl(sclq, g * 4 + 3);
#pragma unroll
        for (int i = 0; i < 8; ++i) {
          off[i][0] *= s0; off[i][1] *= s1; off[i][2] *= s2; off[i][3] *= s3;
        }
      }

      // ---- P = exp2(S - m), in-lane partial sum, pack u32 pairs
      float psum = 0.f;
      unsigned pk[4][2];
#pragma unroll
      for (int ni = 0; ni < 4; ++ni) {
        float p0 = exp2f(sc[ni][0] - mrun);
        float p1 = exp2f(sc[ni][1] - mrun);
        float p2 = exp2f(sc[ni][2] - mrun);
        float p3 = exp2f(sc[ni][3] - mrun);
        psum += (p0 + p1) + (p2 + p3);
        pk[ni][0] = (unsigned)f2b(p0) | ((unsigned)f2b(p1) << 16);
        pk[ni][1] = (unsigned)f2b(p2) | ((unsigned)f2b(p3) << 16);
      }
      psum += __shfl_xor(psum, 16);
      psum += __shfl_xor(psum, 32);
      lrun += psum;

      // ---- P row (q=r) -> per-wave swizzled LDS (8x ds_write_b32)
      {
        char* pw = (char*)&Plds[w][0];
        int base = r * 128;
        int sw = (r & 7) << 4;
#pragma unroll
        for (int ni = 0; ni < 4; ++ni) {
#pragma unroll
          for (int hh = 0; hh < 2; ++hh)
            *(unsigned*)(pw + ((base + ni * 32 + g * 8 + hh * 4) ^ sw)) = pk[ni][hh];
        }
      }
      bf16x8 pa[2];
      {
        const char* pw = (const char*)&Plds[w][0];
        int sw = (r & 7) << 4;
#pragma unroll
        for (int kk = 0; kk < 2; ++kk)
          pa[kk] = *(const bf16x8*)(pw + ((r * 128 + kk * 64 + g * 16) ^ sw));
      }

      // ---- O += P V : B-operand col(d)=dd*16+r, k(kv)=kk*32+g*8+e
#pragma unroll
      for (int dd = 0; dd < 8; ++dd) {
        int d = dd * 16 + r;
#pragma unroll
        for (int kk = 0; kk < 2; ++kk) {
          int ph = (kk * 4 + g) ^ ((r >> 1) & 7);
          bf16x8 vf = *(const bf16x8*)((const char*)Vt + (size_t)d * 128 + ph * 16);
          off[dd] = __builtin_amdgcn_mfma_f32_16x16x32_bf16(pa[kk], vf, off[dd], 0, 0, 0);
        }
      }
      __syncthreads();  // all waves done with Ks/Vt before restage
    }

    // ---- epilogue: O rows q16 = g*4+j; 1/lrun lives at lane r = q16
    float il = 1.0f / lrun;
    float il0 = __shfl(il, g * 4 + 0);
    float il1 = __shfl(il, g * 4 + 1);
    float il2 = __shfl(il, g * 4 + 2);
    float il3 = __shfl(il, g * 4 + 3);
    const size_t orow_base = (size_t)b * 2048 + qt * 64 + w * 16 + g * 4;
#pragma unroll
    for (int dd = 0; dd < 8; ++dd) {
      AO[(orow_base + 0) * 4096 + h * 128 + dd * 16 + r] = f2b(off[dd][0] * il0);
      AO[(orow_base + 1) * 4096 + h * 128 + dd * 16 + r] = f2b(off[dd][1] * il1);
      AO[(orow_base + 2) * 4096 + h * 128 + dd * 16 + r] = f2b(off[dd][2] * il2);
      AO[(orow_base + 3) * 4096 + h * 128 + dd * 16 + r] = f2b(off[dd][3] * il3);
    }
  }
}

// ---------------- launch ----------------
extern "C" void kernel_launch(void* const* d_in, const int* in_sizes, int n_in,
                              void* d_out, int out_size, void* d_ws, size_t ws_size,
                              hipStream_t stream) {
  (void)in_sizes; (void)n_in; (void)out_size; (void)ws_size;
  const float* hs = (const float*)d_in[0];
  const float* cosT = (const float*)d_in[1];
  const float* sinT = (const float*)d_in[2];
  const float* wq = (const float*)d_in[3];
  const float* wk = (const float*)d_in[4];
  const float* wv = (const float*)d_in[5];
  const float* wo = (const float*)d_in[6];
  const float* qnw = (const float*)d_in[7];
  const float* knw = (const float*)d_in[8];
  float* out = (float*)d_out;

  char* ws = (char*)d_ws;
  u16* hsb  = (u16*)(ws);                   // [4096,2048]      16 MB
  u16* wqkv = (u16*)(ws + 16777216);        // [6144,2048]      24 MB
  u16* wob  = (u16*)(ws + 41943040);        // [2048,4096]      16 MB
  u16* Qb   = (u16*)(ws + 58720256);        // [2,32,2048,128]  32 MB
  u16* Kb   = (u16*)(ws + 92274688);        // [2,8,2048,128]    8 MB
  u16* VTb  = (u16*)(ws + 100663296);       // [2,8,128,2048]    8 MB (transposed)
  u16* AO   = (u16*)(ws + 109051904);       // [4096,4096]      32 MB

  // 1) fp32 -> bf16
  cvt_bf16<<<4096, 256, 0, stream>>>(hs, hsb, 1048576);
  cvt_bf16<<<4096, 256, 0, stream>>>(wq, wqkv, 1048576);
  cvt_bf16<<<1024, 256, 0, stream>>>(wk, wqkv + (size_t)4096 * 2048, 262144);
  cvt_bf16<<<1024, 256, 0, stream>>>(wv, wqkv + (size_t)5120 * 2048, 262144);
  cvt_bf16<<<4096, 256, 0, stream>>>(wo, wob, 1048576);

  // 2) fused QKV projection, scatter into [B,H,S,D] (V transposed)
  gemm_bt<0><<<dim3(48, 32), 256, 0, stream>>>(hsb, wqkv, Qb, Kb, VTb, nullptr,
                                               4096, 6144, 2048);

  // 3) per-head RMSNorm + RoPE (Q gets softmax scale * log2e folded in)
  rms_rope<<<32768, 256, 0, stream>>>(Qb, cosT, sinT, qnw, 131072,
                                      0.08838834764831845f * 1.4426950408889634f);
  rms_rope<<<8192, 256, 0, stream>>>(Kb, cosT, sinT, knw, 32768, 1.0f);

  // 4) causal GQA flash attention (paired Q-tiles) -> AO [B*S, 4096] bf16
  attn_fwd<<<dim3(16, 32, 2), 256, 0, stream>>>(Qb, Kb, VTb, AO);

  // 5) output projection -> fp32 d_out
  gemm_bt<1><<<dim3(16, 32), 256, 0, stream>>>(AO, wob, nullptr, nullptr, nullptr,
                                               out, 4096, 2048, 4096);
}

// Round 6
// 428.025 us; speedup vs baseline: 1.1431x; 1.1431x over previous
//
#include <hip/hip_runtime.h>

typedef unsigned short u16;
typedef __attribute__((ext_vector_type(8))) short bf16x8;
typedef __attribute__((ext_vector_type(4))) float f32x4;
typedef __attribute__((ext_vector_type(4))) unsigned int u32x4;

#define GAS __attribute__((address_space(1)))
#define LAS __attribute__((address_space(3)))
#define MFMA __builtin_amdgcn_mfma_f32_16x16x32_bf16
#define BAR() __builtin_amdgcn_s_barrier()
#define WAITV(n) asm volatile("s_waitcnt vmcnt(" #n ")" ::: "memory")

__device__ __forceinline__ void gload16(const void* g, void* l) {
  __builtin_amdgcn_global_load_lds((GAS void*)g, (LAS void*)l, 16, 0, 0);
}
__device__ __forceinline__ u16 f2b(float x) {
  union { float f; unsigned u; } c; c.f = x;
  unsigned r = c.u + 0x7fffu + ((c.u >> 16) & 1u);
  return (u16)(r >> 16);
}
__device__ __forceinline__ float b2f(u16 h) {
  union { unsigned u; float f; } c; c.u = ((unsigned)h) << 16;
  return c.f;
}

// ---------------- fp32 -> bf16 conversion (8 elems/thread) ----------------
__global__ __launch_bounds__(256) void cvt_bf16(const float* __restrict__ src,
                                                u16* __restrict__ dst, int n8) {
  int i = blockIdx.x * 256 + threadIdx.x;
  if (i >= n8) return;
  const float4* s4 = (const float4*)src;
  float4 a = s4[(size_t)i * 2], b = s4[(size_t)i * 2 + 1];
  u32x4 v;
  v[0] = (unsigned)f2b(a.x) | ((unsigned)f2b(a.y) << 16);
  v[1] = (unsigned)f2b(a.z) | ((unsigned)f2b(a.w) << 16);
  v[2] = (unsigned)f2b(b.x) | ((unsigned)f2b(b.y) << 16);
  v[3] = (unsigned)f2b(b.z) | ((unsigned)f2b(b.w) << 16);
  *(u32x4*)(dst + (size_t)i * 8) = v;
}

// ============ 256x256 8-phase QKV GEMM (T2+T3+T4+T5) ============
// C[m,n] = sum_k A[m,k]*B[n,k]. 8 waves (2M x 4N), BK=64, dbuf LDS 128KB.
// LDS granule swizzle (involution): phys_kg = kg ^ (row&7), 16B granules.
// Per tile t: 4 phases; phase q computes mi{2q,2q+1} x ni{0..3} x kk{0,1}.
// Prefetch of tile t+1 per phase: q0:B half0(c0,c1) q1:B half1 q2:A c0 of both
// halves q3:A c1 of both halves. WAITV(4) end of q1, WAITV(2) end of q3.
// Invariant: entering tile t, outstanding = {A0c1,A1c1} of tile t only.
// Scatter epilogue: Q[B,32,S,128], K[B,8,S,128], V normal [B,8,S,128].
__global__ __launch_bounds__(512, 2) void gemm_qkv(
    const u16* __restrict__ A, const u16* __restrict__ B,
    u16* __restrict__ Dq, u16* __restrict__ Dk, u16* __restrict__ Dv,
    int K, int tilesN, int nwg) {
  __shared__ __attribute__((aligned(16))) u16 lds[2][2][2][128 * 64];
  const int tid = threadIdx.x;
  const int lane = tid & 63;
  const int w = tid >> 6;
  const int wr = w >> 2, wc = w & 3;
  const int r = lane & 15, g = lane >> 4;

  int wg = blockIdx.x;
  const int cpx = nwg >> 3;
  wg = (wg & 7) * cpx + (wg >> 3);
  const int bx = wg % tilesN, by = wg / tilesN;
  const size_t m0 = (size_t)by * 256, n0 = (size_t)bx * 256;
  const int NT = K >> 6;

  auto stage = [&](int dbuf, int op, int half, int c, int k0) {
    int slot = c * 512 + tid;
    int row = slot >> 3;
    int kg = (slot & 7) ^ (row & 7);
    const u16* src = (op == 0)
        ? A + (m0 + half * 128 + row) * (size_t)K + k0 + kg * 8
        : B + (n0 + half * 128 + row) * (size_t)K + k0 + kg * 8;
    gload16(src, (char*)&lds[dbuf][op][half][0] + c * 8192 + w * 1024);
  };
  auto ldA = [&](int cur, int mi, int kk) -> bf16x8 {
    int rowl = mi * 16 + r;
    return *(const bf16x8*)((const char*)&lds[cur][0][wr][0] + rowl * 128 +
                            (((kk << 2) + g) ^ (rowl & 7)) * 16);
  };
  auto ldB = [&](int cur, int ni, int kk) -> bf16x8 {
    int rowl = (wc & 1) * 64 + ni * 16 + r;
    return *(const bf16x8*)((const char*)&lds[cur][1][wc >> 1][0] + rowl * 128 +
                            (((kk << 2) + g) ^ (rowl & 7)) * 16);
  };

  f32x4 acc[8][4];
#pragma unroll
  for (int i = 0; i < 8; ++i)
#pragma unroll
    for (int j = 0; j < 4; ++j) acc[i][j] = (f32x4){0.f, 0.f, 0.f, 0.f};

  // ---- prologue: tile 0, order B0c0,B0c1,B1c0,B1c1,A0c0,A1c0,A0c1,A1c1
  stage(0, 1, 0, 0, 0); stage(0, 1, 0, 1, 0);
  stage(0, 1, 1, 0, 0); stage(0, 1, 1, 1, 0);
  stage(0, 0, 0, 0, 0); stage(0, 0, 1, 0, 0);
  stage(0, 0, 0, 1, 0); stage(0, 0, 1, 1, 0);
  WAITV(2);
  BAR();

  bf16x8 bf_[4][2];

#define GPHASE(MI0, IS0, IS1, WAITCODE)                                    \
  {                                                                        \
    bf16x8 aA0 = ldA(cur, MI0, 0), aA1 = ldA(cur, MI0, 1);                 \
    bf16x8 aB0 = ldA(cur, MI0 + 1, 0), aB1 = ldA(cur, MI0 + 1, 1);         \
    IS0; IS1;                                                              \
    BAR();                                                                 \
    __builtin_amdgcn_s_setprio(1);                                         \
    _Pragma("unroll") for (int ni = 0; ni < 4; ++ni) {                     \
      acc[MI0][ni] = MFMA(aA0, bf_[ni][0], acc[MI0][ni], 0, 0, 0);         \
      acc[MI0][ni] = MFMA(aA1, bf_[ni][1], acc[MI0][ni], 0, 0, 0);         \
      acc[MI0 + 1][ni] = MFMA(aB0, bf_[ni][0], acc[MI0 + 1][ni], 0, 0, 0); \
      acc[MI0 + 1][ni] = MFMA(aB1, bf_[ni][1], acc[MI0 + 1][ni], 0, 0, 0); \
    }                                                                      \
    __builtin_amdgcn_s_setprio(0);                                         \
    WAITCODE;                                                              \
    BAR();                                                                 \
  }

  for (int t = 0; t < NT - 1; ++t) {
    const int cur = t & 1, nb = cur ^ 1;
    const int k1 = (t + 1) << 6;
#pragma unroll
    for (int ni = 0; ni < 4; ++ni) {
      bf_[ni][0] = ldB(cur, ni, 0);
      bf_[ni][1] = ldB(cur, ni, 1);
    }
    GPHASE(0, stage(nb, 1, 0, 0, k1), stage(nb, 1, 0, 1, k1), );
    GPHASE(2, stage(nb, 1, 1, 0, k1), stage(nb, 1, 1, 1, k1), WAITV(4));
    GPHASE(4, stage(nb, 0, 0, 0, k1), stage(nb, 0, 1, 0, k1), );
    GPHASE(6, stage(nb, 0, 0, 1, k1), stage(nb, 0, 1, 1, k1), WAITV(2));
  }
  // ---- epilogue tile (no prefetch; drain remaining A c1 after phase 1)
  {
    const int cur = (NT - 1) & 1;
#pragma unroll
    for (int ni = 0; ni < 4; ++ni) {
      bf_[ni][0] = ldB(cur, ni, 0);
      bf_[ni][1] = ldB(cur, ni, 1);
    }
    GPHASE(0, , , );
    GPHASE(2, , , WAITV(0));
    GPHASE(4, , , );
    GPHASE(6, , , );
  }
#undef GPHASE

  // ---- scatter epilogue (n-branch uniform per block: tile never straddles)
#pragma unroll
  for (int mi = 0; mi < 8; ++mi)
#pragma unroll
    for (int ni = 0; ni < 4; ++ni)
#pragma unroll
      for (int j = 0; j < 4; ++j) {
        int m = (int)m0 + wr * 128 + mi * 16 + g * 4 + j;
        int n = (int)n0 + wc * 64 + ni * 16 + r;
        u16 hv = f2b(acc[mi][ni][j]);
        int b = m >> 11, s = m & 2047;
        if (n < 4096) {
          Dq[(((size_t)b * 32 + (n >> 7)) * 2048 + s) * 128 + (n & 127)] = hv;
        } else if (n < 5120) {
          int nn = n - 4096;
          Dk[(((size_t)b * 8 + (nn >> 7)) * 2048 + s) * 128 + (nn & 127)] = hv;
        } else {
          int nn = n - 5120;
          Dv[(((size_t)b * 8 + (nn >> 7)) * 2048 + s) * 128 + (nn & 127)] = hv;
        }
      }
}

// ---------------- V transpose: [16][2048][128] -> [16][128][2048] ----------------
__global__ __launch_bounds__(256) void transpose_v(const u16* __restrict__ V,
                                                   u16* __restrict__ VT) {
  __shared__ __attribute__((aligned(16))) u16 tile[64 * 72];
  const int tid = threadIdx.x;
  const int s0 = blockIdx.x * 64, d0 = blockIdx.y * 64, hz = blockIdx.z;
#pragma unroll
  for (int pp = 0; pp < 2; ++pp) {
    int row = pp * 32 + (tid >> 3), colg = tid & 7;
    u32x4 vv = *(const u32x4*)(V + ((size_t)hz * 2048 + s0 + row) * 128 + d0 + colg * 8);
    *(u32x4*)(&tile[row * 72 + colg * 8]) = vv;
  }
  __syncthreads();
#pragma unroll
  for (int pp = 0; pp < 2; ++pp) {
    int dr = pp * 32 + (tid >> 3), sg = tid & 7;
    u32x4 ov;
#pragma unroll
    for (int e2 = 0; e2 < 4; ++e2)
      ov[e2] = (unsigned)tile[(sg * 8 + 2 * e2) * 72 + dr] |
               ((unsigned)tile[(sg * 8 + 2 * e2 + 1) * 72 + dr] << 16);
    *(u32x4*)(VT + ((size_t)hz * 128 + d0 + dr) * 2048 + s0 + sg * 8) = ov;
  }
}

// ---------------- legacy 128x128 GEMM (fp32 out), used for out-proj ----------------
__global__ __launch_bounds__(256) void gemm_out(
    const u16* __restrict__ A, const u16* __restrict__ B,
    float* __restrict__ Dout, int K) {
  __shared__ __attribute__((aligned(16))) u16 As[128 * 32];
  __shared__ __attribute__((aligned(16))) u16 Bs[128 * 32];
  const int tid = threadIdx.x;
  const int lane = tid & 63;
  const int w = tid >> 6;
  const int wr = w >> 1, wc = w & 1;
  const int r = lane & 15, g = lane >> 4;
  const int m0 = blockIdx.y * 128, n0 = blockIdx.x * 128;

  f32x4 acc[4][4];
#pragma unroll
  for (int i = 0; i < 4; ++i)
#pragma unroll
    for (int j = 0; j < 4; ++j) acc[i][j] = (f32x4){0.f, 0.f, 0.f, 0.f};

  for (int k0 = 0; k0 < K; k0 += 32) {
#pragma unroll
    for (int c = 0; c < 2; ++c) {
      int t = c * 256 + tid;
      int row = t >> 2;
      int kc = (t & 3) ^ ((t >> 2) & 3);
      gload16(A + (size_t)(m0 + row) * K + k0 + kc * 8, (char*)As + c * 4096 + w * 1024);
      gload16(B + (size_t)(n0 + row) * K + k0 + kc * 8, (char*)Bs + c * 4096 + w * 1024);
    }
    __syncthreads();

    bf16x8 af[4], bfr[4];
#pragma unroll
    for (int mi = 0; mi < 4; ++mi) {
      int ro = wr * 64 + mi * 16 + r;
      int slot = (ro * 4 + g) ^ (ro & 3);
      af[mi] = *(const bf16x8*)((const char*)As + slot * 16);
    }
#pragma unroll
    for (int ni = 0; ni < 4; ++ni) {
      int ro = wc * 64 + ni * 16 + r;
      int slot = (ro * 4 + g) ^ (ro & 3);
      bfr[ni] = *(const bf16x8*)((const char*)Bs + slot * 16);
    }
#pragma unroll
    for (int mi = 0; mi < 4; ++mi)
#pragma unroll
      for (int ni = 0; ni < 4; ++ni)
        acc[mi][ni] = MFMA(af[mi], bfr[ni], acc[mi][ni], 0, 0, 0);
    __syncthreads();
  }
#pragma unroll
  for (int mi = 0; mi < 4; ++mi)
#pragma unroll
    for (int ni = 0; ni < 4; ++ni)
#pragma unroll
      for (int j = 0; j < 4; ++j) {
        int m = m0 + wr * 64 + mi * 16 + g * 4 + j;
        int n = n0 + wc * 64 + ni * 16 + r;
        Dout[(size_t)m * 2048 + n] = acc[mi][ni][j];
      }
}

// ---------------- fused per-head RMSNorm + RoPE (in place, bf16) ----------------
__global__ __launch_bounds__(256) void rms_rope(u16* __restrict__ X,
                                                const float* __restrict__ cosT,
                                                const float* __restrict__ sinT,
                                                const float* __restrict__ nw,
                                                int nrows, float oscale) {
  int idx = blockIdx.x * 256 + threadIdx.x;
  int row = idx >> 6;
  int lane = idx & 63;
  if (row >= nrows) return;
  int s = row & 2047;  // S = 2048
  u16* rp = X + (size_t)row * 128;
  float x0 = b2f(rp[lane]);
  float x1 = b2f(rp[lane + 64]);
  float ss = x0 * x0 + x1 * x1;
#pragma unroll
  for (int m = 32; m >= 1; m >>= 1) ss += __shfl_xor(ss, m);
  float inv = rsqrtf(ss * (1.0f / 128.0f) + 1e-6f);
  x0 *= inv * nw[lane];
  x1 *= inv * nw[lane + 64];
  float c0 = cosT[s * 128 + lane], s0 = sinT[s * 128 + lane];
  float c1 = cosT[s * 128 + lane + 64], s1 = sinT[s * 128 + lane + 64];
  rp[lane] = f2b((x0 * c0 - x1 * s0) * oscale);
  rp[lane + 64] = f2b((x1 * c1 + x0 * s1) * oscale);
}

// ---------------- causal GQA flash attention (paired Q-tiles) ----------------
__global__ __launch_bounds__(256) void attn_fwd(const u16* __restrict__ Q,
                                                const u16* __restrict__ Kg,
                                                const u16* __restrict__ Vg,
                                                u16* __restrict__ AO) {
  __shared__ __attribute__((aligned(16))) u16 Ks[64 * 128];
  __shared__ __attribute__((aligned(16))) u16 Vt[128 * 64];
  __shared__ __attribute__((aligned(16))) u16 Plds[4][16 * 64];
  const int tid = threadIdx.x;
  const int lane = tid & 63;
  const int w = tid >> 6;
  const int r = lane & 15, g = lane >> 4;
  const int p = blockIdx.x, h = blockIdx.y, b = blockIdx.z;
  const int hkv = h >> 2;

  const u16* Kp = Kg + (((size_t)b * 8 + hkv) * 2048) * 128;
  const u16* Vp = Vg + (((size_t)b * 8 + hkv) * 128) * 2048;  // transposed head base

#pragma unroll 1
  for (int phase = 0; phase < 2; ++phase) {
    const int qt = phase == 0 ? (31 - p) : p;
    const u16* Qp = Q + (((size_t)b * 32 + h) * 2048 + qt * 64 + w * 16) * 128;

    bf16x8 qf[4];
#pragma unroll
    for (int kk = 0; kk < 4; ++kk)
      qf[kk] = *(const bf16x8*)(Qp + r * 128 + kk * 32 + g * 8);

    f32x4 off[8];
#pragma unroll
    for (int i = 0; i < 8; ++i) off[i] = (f32x4){0.f, 0.f, 0.f, 0.f};
    float mrun = -1e30f, lrun = 0.f;  // per-lane: q-row = w*16 + r

    const int qg = qt * 64 + w * 16 + r;
    const int nu = qt + 1;

    for (int kt = 0; kt < nu; ++kt) {
#pragma unroll
      for (int c = 0; c < 4; ++c) {
        int t = c * 256 + tid;
        int krow = t >> 4;
        int kcc = (t & 15) ^ (krow & 7);
        gload16(Kp + (size_t)(kt * 64 + krow) * 128 + kcc * 8,
                (char*)Ks + c * 4096 + w * 1024);
      }
#pragma unroll
      for (int c = 0; c < 4; ++c) {
        int t = c * 256 + tid;
        int d = t >> 3;
        int kvg = (t & 7) ^ ((d >> 1) & 7);
        gload16(Vp + (size_t)d * 2048 + kt * 64 + kvg * 8,
                (char*)Vt + c * 4096 + w * 1024);
      }
      __syncthreads();

      f32x4 sc[4];
#pragma unroll
      for (int ni = 0; ni < 4; ++ni) {
        f32x4 a = (f32x4){0.f, 0.f, 0.f, 0.f};
        int ro = ni * 16 + r;
#pragma unroll
        for (int kk = 0; kk < 4; ++kk) {
          int slot = (ro * 16 + kk * 4 + g) ^ (ro & 7);
          bf16x8 kf = *(const bf16x8*)((const char*)Ks + slot * 16);
          a = MFMA(kf, qf[kk], a, 0, 0, 0);
        }
        sc[ni] = a;
      }

      float pm = -3e30f;
      if (kt == qt) {
#pragma unroll
        for (int ni = 0; ni < 4; ++ni)
#pragma unroll
          for (int j = 0; j < 4; ++j) {
            int kvg = kt * 64 + ni * 16 + g * 4 + j;
            float sv = sc[ni][j];
            sv = (kvg > qg) ? -1e30f : sv;
            sc[ni][j] = sv;
            pm = fmaxf(pm, sv);
          }
      } else {
#pragma unroll
        for (int ni = 0; ni < 4; ++ni)
#pragma unroll
          for (int j = 0; j < 4; ++j) pm = fmaxf(pm, sc[ni][j]);
      }
      pm = fmaxf(pm, __shfl_xor(pm, 16));
      pm = fmaxf(pm, __shfl_xor(pm, 32));

      if (__any(pm > mrun + 11.0f)) {
        float mn = fmaxf(mrun, pm);
        float sclq = exp2f(mrun - mn);
        mrun = mn;
        lrun *= sclq;
        float s0 = __shfl(sclq, g * 4 + 0);
        float s1 = __shfl(sclq, g * 4 + 1);
        float s2 = __shfl(sclq, g * 4 + 2);
        float s3 = __shfl(sclq, g * 4 + 3);
#pragma unroll
        for (int i = 0; i < 8; ++i) {
          off[i][0] *= s0; off[i][1] *= s1; off[i][2] *= s2; off[i][3] *= s3;
        }
      }

      float psum = 0.f;
      unsigned pk[4][2];
#pragma unroll
      for (int ni = 0; ni < 4; ++ni) {
        float p0 = exp2f(sc[ni][0] - mrun);
        float p1 = exp2f(sc[ni][1] - mrun);
        float p2 = exp2f(sc[ni][2] - mrun);
        float p3 = exp2f(sc[ni][3] - mrun);
        psum += (p0 + p1) + (p2 + p3);
        pk[ni][0] = (unsigned)f2b(p0) | ((unsigned)f2b(p1) << 16);
        pk[ni][1] = (unsigned)f2b(p2) | ((unsigned)f2b(p3) << 16);
      }
      psum += __shfl_xor(psum, 16);
      psum += __shfl_xor(psum, 32);
      lrun += psum;

      {
        char* pw = (char*)&Plds[w][0];
        int base = r * 128;
        int sw = (r & 7) << 4;
#pragma unroll
        for (int ni = 0; ni < 4; ++ni) {
#pragma unroll
          for (int hh = 0; hh < 2; ++hh)
            *(unsigned*)(pw + ((base + ni * 32 + g * 8 + hh * 4) ^ sw)) = pk[ni][hh];
        }
      }
      bf16x8 pa[2];
      {
        const char* pw = (const char*)&Plds[w][0];
        int sw = (r & 7) << 4;
#pragma unroll
        for (int kk = 0; kk < 2; ++kk)
          pa[kk] = *(const bf16x8*)(pw + ((r * 128 + kk * 64 + g * 16) ^ sw));
      }

#pragma unroll
      for (int dd = 0; dd < 8; ++dd) {
        int d = dd * 16 + r;
#pragma unroll
        for (int kk = 0; kk < 2; ++kk) {
          int ph = (kk * 4 + g) ^ ((r >> 1) & 7);
          bf16x8 vf = *(const bf16x8*)((const char*)Vt + (size_t)d * 128 + ph * 16);
          off[dd] = MFMA(pa[kk], vf, off[dd], 0, 0, 0);
        }
      }
      __syncthreads();
    }

    float il = 1.0f / lrun;
    float il0 = __shfl(il, g * 4 + 0);
    float il1 = __shfl(il, g * 4 + 1);
    float il2 = __shfl(il, g * 4 + 2);
    float il3 = __shfl(il, g * 4 + 3);
    const size_t orow_base = (size_t)b * 2048 + qt * 64 + w * 16 + g * 4;
#pragma unroll
    for (int dd = 0; dd < 8; ++dd) {
      AO[(orow_base + 0) * 4096 + h * 128 + dd * 16 + r] = f2b(off[dd][0] * il0);
      AO[(orow_base + 1) * 4096 + h * 128 + dd * 16 + r] = f2b(off[dd][1] * il1);
      AO[(orow_base + 2) * 4096 + h * 128 + dd * 16 + r] = f2b(off[dd][2] * il2);
      AO[(orow_base + 3) * 4096 + h * 128 + dd * 16 + r] = f2b(off[dd][3] * il3);
    }
  }
}

// ---------------- launch ----------------
extern "C" void kernel_launch(void* const* d_in, const int* in_sizes, int n_in,
                              void* d_out, int out_size, void* d_ws, size_t ws_size,
                              hipStream_t stream) {
  (void)in_sizes; (void)n_in; (void)out_size; (void)ws_size;
  const float* hs = (const float*)d_in[0];
  const float* cosT = (const float*)d_in[1];
  const float* sinT = (const float*)d_in[2];
  const float* wq = (const float*)d_in[3];
  const float* wk = (const float*)d_in[4];
  const float* wv = (const float*)d_in[5];
  const float* wo = (const float*)d_in[6];
  const float* qnw = (const float*)d_in[7];
  const float* knw = (const float*)d_in[8];
  float* out = (float*)d_out;

  char* ws = (char*)d_ws;
  u16* hsb  = (u16*)(ws);                   // [4096,2048]      16 MB
  u16* wqkv = (u16*)(ws + 16777216);        // [6144,2048]      24 MB
  u16* wob  = (u16*)(ws + 41943040);        // [2048,4096]      16 MB
  u16* Qb   = (u16*)(ws + 58720256);        // [2,32,2048,128]  32 MB
  u16* Kb   = (u16*)(ws + 92274688);        // [2,8,2048,128]    8 MB
  u16* VTb  = (u16*)(ws + 100663296);       // [2,8,128,2048]    8 MB (transposed)
  u16* AO   = (u16*)(ws + 109051904);       // [4096,4096]      32 MB
  u16* Vnrm = AO;                           // [2,8,2048,128]    8 MB, dead before attn

  // 1) fp32 -> bf16
  cvt_bf16<<<4096, 256, 0, stream>>>(hs, hsb, 1048576);
  cvt_bf16<<<4096, 256, 0, stream>>>(wq, wqkv, 1048576);
  cvt_bf16<<<1024, 256, 0, stream>>>(wk, wqkv + (size_t)4096 * 2048, 262144);
  cvt_bf16<<<1024, 256, 0, stream>>>(wv, wqkv + (size_t)5120 * 2048, 262144);
  cvt_bf16<<<4096, 256, 0, stream>>>(wo, wob, 1048576);

  // 2) fused QKV projection (256^2 8-phase), V in normal layout
  gemm_qkv<<<384, 512, 0, stream>>>(hsb, wqkv, Qb, Kb, Vnrm, 2048, 24, 384);

  // 2b) V -> V^T [b,hkv,d,s]
  transpose_v<<<dim3(32, 2, 16), 256, 0, stream>>>(Vnrm, VTb);

  // 3) per-head RMSNorm + RoPE (Q gets softmax scale * log2e folded in)
  rms_rope<<<32768, 256, 0, stream>>>(Qb, cosT, sinT, qnw, 131072,
                                      0.08838834764831845f * 1.4426950408889634f);
  rms_rope<<<8192, 256, 0, stream>>>(Kb, cosT, sinT, knw, 32768, 1.0f);

  // 4) causal GQA flash attention (paired Q-tiles) -> AO [B*S, 4096] bf16
  attn_fwd<<<dim3(16, 32, 2), 256, 0, stream>>>(Qb, Kb, VTb, AO);

  // 5) output projection -> fp32 d_out
  gemm_out<<<dim3(16, 32), 256, 0, stream>>>(AO, wob, out, 4096);
}

// Round 7
// 406.667 us; speedup vs baseline: 1.2031x; 1.0525x over previous
//
#include <hip/hip_runtime.h>

typedef unsigned short u16;
typedef __attribute__((ext_vector_type(8))) short bf16x8;
typedef __attribute__((ext_vector_type(4))) float f32x4;
typedef __attribute__((ext_vector_type(4))) unsigned int u32x4;

#define GAS __attribute__((address_space(1)))
#define LAS __attribute__((address_space(3)))
#define MFMA __builtin_amdgcn_mfma_f32_16x16x32_bf16
#define BAR() __builtin_amdgcn_s_barrier()
#define WAITV(n) asm volatile("s_waitcnt vmcnt(" #n ")" ::: "memory")

__device__ __forceinline__ void gload16(const void* g, void* l) {
  __builtin_amdgcn_global_load_lds((GAS void*)g, (LAS void*)l, 16, 0, 0);
}
__device__ __forceinline__ u16 f2b(float x) {
  union { float f; unsigned u; } c; c.f = x;
  unsigned r = c.u + 0x7fffu + ((c.u >> 16) & 1u);
  return (u16)(r >> 16);
}
__device__ __forceinline__ float b2f(u16 h) {
  union { unsigned u; float f; } c; c.u = ((unsigned)h) << 16;
  return c.f;
}
__device__ __forceinline__ unsigned cvtpk(float lo, float hi) {
  unsigned r;
  asm("v_cvt_pk_bf16_f32 %0, %1, %2" : "=v"(r) : "v"(lo), "v"(hi));
  return r;
}

// ---------------- fp32 -> bf16 conversion (8 elems/thread) ----------------
__global__ __launch_bounds__(256) void cvt_bf16(const float* __restrict__ src,
                                                u16* __restrict__ dst, int n8) {
  int i = blockIdx.x * 256 + threadIdx.x;
  if (i >= n8) return;
  const float4* s4 = (const float4*)src;
  float4 a = s4[(size_t)i * 2], b = s4[(size_t)i * 2 + 1];
  u32x4 v;
  v[0] = (unsigned)f2b(a.x) | ((unsigned)f2b(a.y) << 16);
  v[1] = (unsigned)f2b(a.z) | ((unsigned)f2b(a.w) << 16);
  v[2] = (unsigned)f2b(b.x) | ((unsigned)f2b(b.y) << 16);
  v[3] = (unsigned)f2b(b.z) | ((unsigned)f2b(b.w) << 16);
  *(u32x4*)(dst + (size_t)i * 8) = v;
}

// ============ 256x256 8-phase GEMM (T2+T3+T4+T5) ============
// C[m,n] = sum_k A[m,k]*B[n,k]. 8 waves (2M x 4N), BK=64, dbuf LDS 128KB.
// LDS granule swizzle (involution): phys_kg = kg ^ (row&7), 16B granules.
// WAITV(4) end of phase 1, WAITV(2) end of phase 3 => entering a tile only
// its own two A-c1 loads are outstanding (counted-vmcnt, never drains to 0).
// MODE 0: scatter Q[B,32,S,128] / K[B,8,S,128] / V normal [B,8,S,128] (bf16)
// MODE 1: fp32 linear epilogue Dout[m * (tilesN*256) + n]
template <int MODE>
__global__ __launch_bounds__(512, 2) void gemm256(
    const u16* __restrict__ A, const u16* __restrict__ B,
    u16* __restrict__ Dq, u16* __restrict__ Dk, u16* __restrict__ Dv,
    float* __restrict__ Dout, int K, int tilesN, int nwg) {
  __shared__ __attribute__((aligned(16))) u16 lds[2][2][2][128 * 64];
  const int tid = threadIdx.x;
  const int lane = tid & 63;
  const int w = tid >> 6;
  const int wr = w >> 2, wc = w & 3;
  const int r = lane & 15, g = lane >> 4;

  int wg = blockIdx.x;
  const int cpx = nwg >> 3;
  wg = (wg & 7) * cpx + (wg >> 3);
  const int bx = wg % tilesN, by = wg / tilesN;
  const size_t m0 = (size_t)by * 256, n0 = (size_t)bx * 256;
  const int NT = K >> 6;

  auto stage = [&](int dbuf, int op, int half, int c, int k0) {
    int slot = c * 512 + tid;
    int row = slot >> 3;
    int kg = (slot & 7) ^ (row & 7);
    const u16* src = (op == 0)
        ? A + (m0 + half * 128 + row) * (size_t)K + k0 + kg * 8
        : B + (n0 + half * 128 + row) * (size_t)K + k0 + kg * 8;
    gload16(src, (char*)&lds[dbuf][op][half][0] + c * 8192 + w * 1024);
  };
  auto ldA = [&](int cur, int mi, int kk) -> bf16x8 {
    int rowl = mi * 16 + r;
    return *(const bf16x8*)((const char*)&lds[cur][0][wr][0] + rowl * 128 +
                            (((kk << 2) + g) ^ (rowl & 7)) * 16);
  };
  auto ldB = [&](int cur, int ni, int kk) -> bf16x8 {
    int rowl = (wc & 1) * 64 + ni * 16 + r;
    return *(const bf16x8*)((const char*)&lds[cur][1][wc >> 1][0] + rowl * 128 +
                            (((kk << 2) + g) ^ (rowl & 7)) * 16);
  };

  f32x4 acc[8][4];
#pragma unroll
  for (int i = 0; i < 8; ++i)
#pragma unroll
    for (int j = 0; j < 4; ++j) acc[i][j] = (f32x4){0.f, 0.f, 0.f, 0.f};

  // ---- prologue: tile 0, order B0c0,B0c1,B1c0,B1c1,A0c0,A1c0,A0c1,A1c1
  stage(0, 1, 0, 0, 0); stage(0, 1, 0, 1, 0);
  stage(0, 1, 1, 0, 0); stage(0, 1, 1, 1, 0);
  stage(0, 0, 0, 0, 0); stage(0, 0, 1, 0, 0);
  stage(0, 0, 0, 1, 0); stage(0, 0, 1, 1, 0);
  WAITV(2);
  BAR();

  bf16x8 bf_[4][2];

#define GPHASE(MI0, IS0, IS1, WAITCODE)                                    \
  {                                                                        \
    bf16x8 aA0 = ldA(cur, MI0, 0), aA1 = ldA(cur, MI0, 1);                 \
    bf16x8 aB0 = ldA(cur, MI0 + 1, 0), aB1 = ldA(cur, MI0 + 1, 1);         \
    IS0; IS1;                                                              \
    BAR();                                                                 \
    __builtin_amdgcn_s_setprio(1);                                         \
    _Pragma("unroll") for (int ni = 0; ni < 4; ++ni) {                     \
      acc[MI0][ni] = MFMA(aA0, bf_[ni][0], acc[MI0][ni], 0, 0, 0);         \
      acc[MI0][ni] = MFMA(aA1, bf_[ni][1], acc[MI0][ni], 0, 0, 0);         \
      acc[MI0 + 1][ni] = MFMA(aB0, bf_[ni][0], acc[MI0 + 1][ni], 0, 0, 0); \
      acc[MI0 + 1][ni] = MFMA(aB1, bf_[ni][1], acc[MI0 + 1][ni], 0, 0, 0); \
    }                                                                      \
    __builtin_amdgcn_s_setprio(0);                                         \
    WAITCODE;                                                              \
    BAR();                                                                 \
  }

  for (int t = 0; t < NT - 1; ++t) {
    const int cur = t & 1, nb = cur ^ 1;
    const int k1 = (t + 1) << 6;
#pragma unroll
    for (int ni = 0; ni < 4; ++ni) {
      bf_[ni][0] = ldB(cur, ni, 0);
      bf_[ni][1] = ldB(cur, ni, 1);
    }
    GPHASE(0, stage(nb, 1, 0, 0, k1), stage(nb, 1, 0, 1, k1), );
    GPHASE(2, stage(nb, 1, 1, 0, k1), stage(nb, 1, 1, 1, k1), WAITV(4));
    GPHASE(4, stage(nb, 0, 0, 0, k1), stage(nb, 0, 1, 0, k1), );
    GPHASE(6, stage(nb, 0, 0, 1, k1), stage(nb, 0, 1, 1, k1), WAITV(2));
  }
  // ---- epilogue tile (no prefetch; drain remaining A c1 after phase 1)
  {
    const int cur = (NT - 1) & 1;
#pragma unroll
    for (int ni = 0; ni < 4; ++ni) {
      bf_[ni][0] = ldB(cur, ni, 0);
      bf_[ni][1] = ldB(cur, ni, 1);
    }
    GPHASE(0, , , );
    GPHASE(2, , , WAITV(0));
    GPHASE(4, , , );
    GPHASE(6, , , );
  }
#undef GPHASE

  // ---- epilogues
#pragma unroll
  for (int mi = 0; mi < 8; ++mi)
#pragma unroll
    for (int ni = 0; ni < 4; ++ni)
#pragma unroll
      for (int j = 0; j < 4; ++j) {
        int m = (int)m0 + wr * 128 + mi * 16 + g * 4 + j;
        int n = (int)n0 + wc * 64 + ni * 16 + r;
        if (MODE == 0) {
          u16 hv = f2b(acc[mi][ni][j]);
          int b = m >> 11, s = m & 2047;
          if (n < 4096) {
            Dq[(((size_t)b * 32 + (n >> 7)) * 2048 + s) * 128 + (n & 127)] = hv;
          } else if (n < 5120) {
            int nn = n - 4096;
            Dk[(((size_t)b * 8 + (nn >> 7)) * 2048 + s) * 128 + (nn & 127)] = hv;
          } else {
            int nn = n - 5120;
            Dv[(((size_t)b * 8 + (nn >> 7)) * 2048 + s) * 128 + (nn & 127)] = hv;
          }
        } else {
          Dout[(size_t)m * (size_t)(tilesN * 256) + n] = acc[mi][ni][j];
        }
      }
}

// ---------------- V transpose: [16][2048][128] -> [16][128][2048] ----------------
__global__ __launch_bounds__(256) void transpose_v(const u16* __restrict__ V,
                                                   u16* __restrict__ VT) {
  __shared__ __attribute__((aligned(16))) u16 tile[64 * 72];
  const int tid = threadIdx.x;
  const int s0 = blockIdx.x * 64, d0 = blockIdx.y * 64, hz = blockIdx.z;
#pragma unroll
  for (int pp = 0; pp < 2; ++pp) {
    int row = pp * 32 + (tid >> 3), colg = tid & 7;
    u32x4 vv = *(const u32x4*)(V + ((size_t)hz * 2048 + s0 + row) * 128 + d0 + colg * 8);
    *(u32x4*)(&tile[row * 72 + colg * 8]) = vv;
  }
  __syncthreads();
#pragma unroll
  for (int pp = 0; pp < 2; ++pp) {
    int dr = pp * 32 + (tid >> 3), sg = tid & 7;
    u32x4 ov;
#pragma unroll
    for (int e2 = 0; e2 < 4; ++e2)
      ov[e2] = (unsigned)tile[(sg * 8 + 2 * e2) * 72 + dr] |
               ((unsigned)tile[(sg * 8 + 2 * e2 + 1) * 72 + dr] << 16);
    *(u32x4*)(VT + ((size_t)hz * 128 + d0 + dr) * 2048 + s0 + sg * 8) = ov;
  }
}

// ---------------- fused per-head RMSNorm + RoPE (in place, bf16) ----------------
__global__ __launch_bounds__(256) void rms_rope(u16* __restrict__ X,
                                                const float* __restrict__ cosT,
                                                const float* __restrict__ sinT,
                                                const float* __restrict__ nw,
                                                int nrows, float oscale) {
  int idx = blockIdx.x * 256 + threadIdx.x;
  int row = idx >> 6;
  int lane = idx & 63;
  if (row >= nrows) return;
  int s = row & 2047;  // S = 2048
  u16* rp = X + (size_t)row * 128;
  float x0 = b2f(rp[lane]);
  float x1 = b2f(rp[lane + 64]);
  float ss = x0 * x0 + x1 * x1;
#pragma unroll
  for (int m = 32; m >= 1; m >>= 1) ss += __shfl_xor(ss, m);
  float inv = rsqrtf(ss * (1.0f / 128.0f) + 1e-6f);
  x0 *= inv * nw[lane];
  x1 *= inv * nw[lane + 64];
  float c0 = cosT[s * 128 + lane], s0 = sinT[s * 128 + lane];
  float c1 = cosT[s * 128 + lane + 64], s1 = sinT[s * 128 + lane + 64];
  rp[lane] = f2b((x0 * c0 - x1 * s0) * oscale);
  rp[lane + 64] = f2b((x1 * c1 + x0 * s1) * oscale);
}

// ---------------- causal GQA flash attention (paired Q-tiles) ----------------
// block p handles Q-tiles {31-p, p}. 4 waves x 16 q-rows, KVBLK=64.
// Swapped QK^T (lane owns q-row w*16+r), exp2 domain, cvt_pk P pack,
// row-sum via ones-MFMA (lrun kept in off distribution), hoisted staging ptrs.
__global__ __launch_bounds__(256) void attn_fwd(const u16* __restrict__ Q,
                                                const u16* __restrict__ Kg,
                                                const u16* __restrict__ Vg,
                                                u16* __restrict__ AO) {
  __shared__ __attribute__((aligned(16))) u16 Ks[64 * 128];
  __shared__ __attribute__((aligned(16))) u16 Vt[128 * 64];
  __shared__ __attribute__((aligned(16))) u16 Plds[4][16 * 64];
  const int tid = threadIdx.x;
  const int lane = tid & 63;
  const int w = tid >> 6;
  const int r = lane & 15, g = lane >> 4;
  const int p = blockIdx.x, h = blockIdx.y, b = blockIdx.z;
  const int hkv = h >> 2;

  const u16* Kp = Kg + (((size_t)b * 8 + hkv) * 2048) * 128;
  const u16* Vp = Vg + (((size_t)b * 8 + hkv) * 128) * 2048;  // transposed head base

  const short one_bf = (short)0x3F80;
  const bf16x8 vones = {one_bf, one_bf, one_bf, one_bf, one_bf, one_bf, one_bf, one_bf};

#pragma unroll 1
  for (int phase = 0; phase < 2; ++phase) {
    const int qt = phase == 0 ? (31 - p) : p;
    const u16* Qp = Q + (((size_t)b * 32 + h) * 2048 + qt * 64 + w * 16) * 128;

    bf16x8 qf[4];
#pragma unroll
    for (int kk = 0; kk < 4; ++kk)
      qf[kk] = *(const bf16x8*)(Qp + r * 128 + kk * 32 + g * 8);

    f32x4 off[8];
#pragma unroll
    for (int i = 0; i < 8; ++i) off[i] = (f32x4){0.f, 0.f, 0.f, 0.f};
    f32x4 lr4 = (f32x4){0.f, 0.f, 0.f, 0.f};  // row-sums, off distribution
    float mrun = -1e30f;                      // per-lane: q-row = w*16 + r

    // hoisted staging source pointers (advance per kt)
    const u16* kst[4];
    const u16* vst[4];
#pragma unroll
    for (int c = 0; c < 4; ++c) {
      int t = c * 256 + tid;
      kst[c] = Kp + (size_t)(t >> 4) * 128 + (size_t)(((t & 15) ^ ((t >> 4) & 7)) * 8);
      int d = t >> 3;
      vst[c] = Vp + (size_t)d * 2048 + (size_t)(((t & 7) ^ ((d >> 1) & 7)) * 8);
    }

    const int qg = qt * 64 + w * 16 + r;
    const int nu = qt + 1;

    for (int kt = 0; kt < nu; ++kt) {
#pragma unroll
      for (int c = 0; c < 4; ++c) {
        gload16(kst[c], (char*)Ks + c * 4096 + w * 1024);
        kst[c] += 64 * 128;
      }
#pragma unroll
      for (int c = 0; c < 4; ++c) {
        gload16(vst[c], (char*)Vt + c * 4096 + w * 1024);
        vst[c] += 64;
      }
      __syncthreads();

      // ---- S^T = K Q^T: D col = q = r, D row = kv = ni*16 + g*4 + j
      f32x4 sc[4];
#pragma unroll
      for (int ni = 0; ni < 4; ++ni) {
        f32x4 a = (f32x4){0.f, 0.f, 0.f, 0.f};
        int ro = ni * 16 + r;
#pragma unroll
        for (int kk = 0; kk < 4; ++kk) {
          int slot = (ro * 16 + kk * 4 + g) ^ (ro & 7);
          bf16x8 kf = *(const bf16x8*)((const char*)Ks + slot * 16);
          a = MFMA(kf, qf[kk], a, 0, 0, 0);
        }
        sc[ni] = a;
      }

      // ---- mask (diagonal unit only) + in-lane max
      float pm = -3e30f;
      if (kt == qt) {
#pragma unroll
        for (int ni = 0; ni < 4; ++ni)
#pragma unroll
          for (int j = 0; j < 4; ++j) {
            int kvg = kt * 64 + ni * 16 + g * 4 + j;
            float sv = sc[ni][j];
            sv = (kvg > qg) ? -1e30f : sv;
            sc[ni][j] = sv;
            pm = fmaxf(pm, sv);
          }
      } else {
#pragma unroll
        for (int ni = 0; ni < 4; ++ni)
#pragma unroll
          for (int j = 0; j < 4; ++j) pm = fmaxf(pm, sc[ni][j]);
      }
      pm = fmaxf(pm, __shfl_xor(pm, 16));
      pm = fmaxf(pm, __shfl_xor(pm, 32));

      // ---- defer-rescale (log2 units, THR=11 ~ e^7.6)
      if (__any(pm > mrun + 11.0f)) {
        float mn = fmaxf(mrun, pm);
        float sclq = exp2f(mrun - mn);
        mrun = mn;
        f32x4 sv4;
        sv4[0] = __shfl(sclq, g * 4 + 0);
        sv4[1] = __shfl(sclq, g * 4 + 1);
        sv4[2] = __shfl(sclq, g * 4 + 2);
        sv4[3] = __shfl(sclq, g * 4 + 3);
#pragma unroll
        for (int i = 0; i < 8; ++i) off[i] *= sv4;
        lr4 *= sv4;
      }

      // ---- P = exp2(S - m), pack via v_cvt_pk_bf16_f32
      unsigned pk[4][2];
#pragma unroll
      for (int ni = 0; ni < 4; ++ni) {
        float p0 = exp2f(sc[ni][0] - mrun);
        float p1 = exp2f(sc[ni][1] - mrun);
        float p2 = exp2f(sc[ni][2] - mrun);
        float p3 = exp2f(sc[ni][3] - mrun);
        pk[ni][0] = cvtpk(p0, p1);
        pk[ni][1] = cvtpk(p2, p3);
      }

      // ---- P row (q=r) -> per-wave swizzled LDS (8x ds_write_b32)
      {
        char* pw = (char*)&Plds[w][0];
        int base = r * 128;
        int sw = (r & 7) << 4;
#pragma unroll
        for (int ni = 0; ni < 4; ++ni) {
#pragma unroll
          for (int hh = 0; hh < 2; ++hh)
            *(unsigned*)(pw + ((base + ni * 32 + g * 8 + hh * 4) ^ sw)) = pk[ni][hh];
        }
      }
      bf16x8 pa[2];
      {
        const char* pw = (const char*)&Plds[w][0];
        int sw = (r & 7) << 4;
#pragma unroll
        for (int kk = 0; kk < 2; ++kk)
          pa[kk] = *(const bf16x8*)(pw + ((r * 128 + kk * 64 + g * 16) ^ sw));
      }

      // ---- row-sum via ones-MFMA (lands in off distribution, row = g*4+j)
      lr4 = MFMA(pa[0], vones, lr4, 0, 0, 0);
      lr4 = MFMA(pa[1], vones, lr4, 0, 0, 0);

      // ---- O += P V : B-operand col(d)=dd*16+r, k(kv)=kk*32+g*8+e
#pragma unroll
      for (int dd = 0; dd < 8; ++dd) {
        int d = dd * 16 + r;
#pragma unroll
        for (int kk = 0; kk < 2; ++kk) {
          int ph = (kk * 4 + g) ^ ((r >> 1) & 7);
          bf16x8 vf = *(const bf16x8*)((const char*)Vt + (size_t)d * 128 + ph * 16);
          off[dd] = MFMA(pa[kk], vf, off[dd], 0, 0, 0);
        }
      }
      __syncthreads();
    }

    // ---- epilogue: O rows q16 = g*4+j; lr4 already in the same distribution
    f32x4 il4;
#pragma unroll
    for (int j = 0; j < 4; ++j) il4[j] = 1.0f / lr4[j];
    const size_t orow_base = (size_t)b * 2048 + qt * 64 + w * 16 + g * 4;
#pragma unroll
    for (int dd = 0; dd < 8; ++dd) {
      AO[(orow_base + 0) * 4096 + h * 128 + dd * 16 + r] = f2b(off[dd][0] * il4[0]);
      AO[(orow_base + 1) * 4096 + h * 128 + dd * 16 + r] = f2b(off[dd][1] * il4[1]);
      AO[(orow_base + 2) * 4096 + h * 128 + dd * 16 + r] = f2b(off[dd][2] * il4[2]);
      AO[(orow_base + 3) * 4096 + h * 128 + dd * 16 + r] = f2b(off[dd][3] * il4[3]);
    }
  }
}

// ---------------- launch ----------------
extern "C" void kernel_launch(void* const* d_in, const int* in_sizes, int n_in,
                              void* d_out, int out_size, void* d_ws, size_t ws_size,
                              hipStream_t stream) {
  (void)in_sizes; (void)n_in; (void)out_size; (void)ws_size;
  const float* hs = (const float*)d_in[0];
  const float* cosT = (const float*)d_in[1];
  const float* sinT = (const float*)d_in[2];
  const float* wq = (const float*)d_in[3];
  const float* wk = (const float*)d_in[4];
  const float* wv = (const float*)d_in[5];
  const float* wo = (const float*)d_in[6];
  const float* qnw = (const float*)d_in[7];
  const float* knw = (const float*)d_in[8];
  float* out = (float*)d_out;

  char* ws = (char*)d_ws;
  u16* hsb  = (u16*)(ws);                   // [4096,2048]      16 MB
  u16* wqkv = (u16*)(ws + 16777216);        // [6144,2048]      24 MB
  u16* wob  = (u16*)(ws + 41943040);        // [2048,4096]      16 MB
  u16* Qb   = (u16*)(ws + 58720256);        // [2,32,2048,128]  32 MB
  u16* Kb   = (u16*)(ws + 92274688);        // [2,8,2048,128]    8 MB
  u16* VTb  = (u16*)(ws + 100663296);       // [2,8,128,2048]    8 MB (transposed)
  u16* AO   = (u16*)(ws + 109051904);       // [4096,4096]      32 MB
  u16* Vnrm = AO;                           // [2,8,2048,128]    8 MB, dead before attn

  // 1) fp32 -> bf16
  cvt_bf16<<<4096, 256, 0, stream>>>(hs, hsb, 1048576);
  cvt_bf16<<<4096, 256, 0, stream>>>(wq, wqkv, 1048576);
  cvt_bf16<<<1024, 256, 0, stream>>>(wk, wqkv + (size_t)4096 * 2048, 262144);
  cvt_bf16<<<1024, 256, 0, stream>>>(wv, wqkv + (size_t)5120 * 2048, 262144);
  cvt_bf16<<<4096, 256, 0, stream>>>(wo, wob, 1048576);

  // 2) fused QKV projection (256^2 8-phase), V in normal layout
  gemm256<0><<<384, 512, 0, stream>>>(hsb, wqkv, Qb, Kb, Vnrm, nullptr, 2048, 24, 384);

  // 2b) V -> V^T [b,hkv,d,s]
  transpose_v<<<dim3(32, 2, 16), 256, 0, stream>>>(Vnrm, VTb);

  // 3) per-head RMSNorm + RoPE (Q gets softmax scale * log2e folded in)
  rms_rope<<<32768, 256, 0, stream>>>(Qb, cosT, sinT, qnw, 131072,
                                      0.08838834764831845f * 1.4426950408889634f);
  rms_rope<<<8192, 256, 0, stream>>>(Kb, cosT, sinT, knw, 32768, 1.0f);

  // 4) causal GQA flash attention (paired Q-tiles) -> AO [B*S, 4096] bf16
  attn_fwd<<<dim3(16, 32, 2), 256, 0, stream>>>(Qb, Kb, VTb, AO);

  // 5) output projection (256^2 8-phase) -> fp32 d_out
  gemm256<1><<<128, 512, 0, stream>>>(AO, wob, nullptr, nullptr, nullptr, out,
                                      4096, 8, 128);
}